// Round 9
// baseline (374.415 us; speedup 1.0000x reference)
//
#include <hip/hip_runtime.h>

// self_attention: x(4,2048,1024) fp32; Q=xWq^T+bq, K=xWk^T+bk, V=xWv^T+bv
// logits = QK^T / sqrt(2048); out = softmax(logits) @ V
//
// R9: hybrid direct-B GEMM (AITER-style K-loop in HIP). The ~660 TF plateau
// comes from __syncthreads having to drain the global_load_lds queue
// (vmcnt(0)). Fix: only A goes through LDS-DMA (4 issues/wave, issued FIRST
// each iter so the barrier can retire them with vmcnt(8), not vmcnt(0));
// B is loaded straight to VGPRs (8x global_load_dwordx4/wave, prefetched
// one iteration ahead; plain register loads need NO drain at a barrier).
// K-loop unrolled 2x for register ping-pong without v_movs (K % 128 == 0).
// LDS drops 64->32 KB. Epilogues/MODEs unchanged from R8 (4 dispatches,
// exp-without-max scores + rowsum atomics + PV normalization).

typedef unsigned short u16;
typedef unsigned int u32;
typedef __bf16 bf16x8 __attribute__((ext_vector_type(8)));
typedef float floatx4 __attribute__((ext_vector_type(4)));

__device__ __forceinline__ u16 f2bf(float f) {
    u32 u = __float_as_uint(f);
    u += 0x7fffu + ((u >> 16) & 1u);   // RNE
    return (u16)(u >> 16);
}

__device__ __forceinline__ void g2lds16(const void* g, void* l) {
    __builtin_amdgcn_global_load_lds(
        (const __attribute__((address_space(1))) unsigned int*)g,
        (__attribute__((address_space(3))) unsigned int*)l,
        16, 0, 0);
}

// ---- fused cast: x -> xb, Wq|Wk|Wv -> wall (3072x1024), zero rowsum ----
__global__ __launch_bounds__(256)
void cvt_all(const float* __restrict__ x, const float* __restrict__ Wq,
             const float* __restrict__ Wk, const float* __restrict__ Wv,
             u16* __restrict__ xb, u16* __restrict__ wall,
             float* __restrict__ rowsum)
{
    const int NX = 2097152;   // B*S*D/4
    const int NW = 262144;    // D*D/4
    const int TOT = NX + 3 * NW;    // 2883584 = 11264 * 256
    int i = blockIdx.x * 256 + threadIdx.x;
    if (i >= TOT) {
        int z = i - TOT;              // 0..2047 -> 8192 floats of rowsum
        float4 zz = {0.f, 0.f, 0.f, 0.f};
        ((float4*)rowsum)[z] = zz;
        return;
    }
    const float* src;
    u16* dst;
    int idx;
    if (i < NX) { src = x; dst = xb; idx = i; }
    else {
        int j = i - NX;
        dst = wall; idx = j;
        src = (j < NW) ? Wq : (j < 2 * NW) ? Wk : Wv;
        int jj = (j < NW) ? j : (j < 2 * NW) ? (j - NW) : (j - 2 * NW);
        float4 v = ((const float4*)src)[jj];
        ushort4 o;
        o.x = f2bf(v.x); o.y = f2bf(v.y); o.z = f2bf(v.z); o.w = f2bf(v.w);
        ((ushort4*)dst)[idx] = o;
        return;
    }
    float4 v = ((const float4*)src)[idx];
    ushort4 o;
    o.x = f2bf(v.x); o.y = f2bf(v.y); o.z = f2bf(v.z); o.w = f2bf(v.w);
    ((ushort4*)dst)[idx] = o;
}

// --------------- GEMM: C[m][n] = sum_k A[m][k]*B[n][k] ------------------
// A: M x K row-major bf16 (LDS-staged, dbuf), B: N x K row-major bf16
// (direct-to-register, prefetch depth 1). 128x128 block, BK=64, 4 waves
// (2m x 2n), wave 64x64 via 4x4 of v_mfma_f32_16x16x32_bf16.
// A-LDS rows 128 B, XOR chunk swizzle (conflict-free). K % 128 == 0.
// C/D layout: col=lane&15, row=quad*4+reg.
// MODE 3: fused QKV. MODE 4: scores exp + rowsum atomics. MODE 5: PV/rowsum.
template<int MODE>
__global__ __launch_bounds__(256)
void gemm_bt(const u16* __restrict__ A, const u16* __restrict__ B,
             void* __restrict__ Out, const float* __restrict__ bias,
             float scale, int M, int N, int K,
             long long sAz, long long sBz, long long sOz,
             void* __restrict__ Out2, void* __restrict__ Out3,
             const float* __restrict__ bias2, const float* __restrict__ bias3,
             float* __restrict__ rowsum)
{
    __shared__ u16 ldsA[2][128 * 64];   // 2 x 16 KB (A only)

    const int tid   = threadIdx.x;
    const int lane  = tid & 63;
    const int wv    = tid >> 6;          // wave 0..3
    const int wm    = (wv >> 1) * 64;
    const int wn    = (wv & 1) * 64;
    const int lhalf = lane & 15;
    const int quad  = lane >> 4;

    const size_t bz = blockIdx.z;
    A += bz * (size_t)sAz;
    B += bz * (size_t)sBz;

    // supertile mapping (GROUP_M=4) for L2 tile reuse
    int tm, tn;
    {
        const int ntn = gridDim.x, ntm = gridDim.y;
        const int lin = blockIdx.y * ntn + blockIdx.x;
        const int GM = 4;
        const int width = GM * ntn;
        const int group = lin / width;
        const int first = group * GM;
        const int gsz   = (ntm - first) < GM ? (ntm - first) : GM;
        const int rem   = lin - group * width;
        tm = first + rem % gsz;
        tn = rem / gsz;
    }
    const int m0 = tm * 128;
    const int n0 = tn * 128;

    // A staging: wave wv, issue j: rows wv*32 + j*8 + (lane>>3),
    // src chunk (lane&7)^(lane>>3)  [stored at phys chunk lane&7]
    const int r8 = lane >> 3;
    const int gc = (lane & 7) ^ r8;
    const u16* pa = A + (size_t)(m0 + wv * 32 + r8) * K + gc * 8;
    const int lofs = wv * 2048;

    // B direct-load base: frag (ks,j) at kb: pbq + kb + j*16*K + ks*32
    const u16* pbq = B + (size_t)(n0 + wn + lhalf) * K + quad * 8;

    floatx4 zero = {0.f, 0.f, 0.f, 0.f};
    floatx4 acc[4][4];
#pragma unroll
    for (int i = 0; i < 4; ++i)
#pragma unroll
        for (int j = 0; j < 4; ++j) acc[i][j] = zero;

    const int swz = lhalf & 7;          // == row&7 for all frag rows

    bf16x8 b0[2][4], b1[2][4];

    // prologue: A(k=0) -> buf0 (DMA), B(k=0) -> b0 (registers)
#pragma unroll
    for (int j = 0; j < 4; ++j)
        g2lds16(pa + (size_t)(j * 8) * K, &ldsA[0][lofs + j * 512]);
    pa += 64;
#pragma unroll
    for (int ks = 0; ks < 2; ++ks)
#pragma unroll
        for (int j = 0; j < 4; ++j)
            b0[ks][j] = *(const bf16x8*)(pbq + (size_t)(j * 16) * K + ks * 32);

    for (int k0 = 0; k0 < K; k0 += 128) {
        // ---- half 0: compute [k0, k0+64) from buf0/b0; stage k0+64 ----
        __syncthreads();   // drains A-DMA (oldest in queue); B-loads exempt
        {
#pragma unroll
            for (int j = 0; j < 4; ++j)
                g2lds16(pa + (size_t)(j * 8) * K, &ldsA[1][lofs + j * 512]);
            pa += 64;
            const u16* pk = pbq + (k0 + 64);
#pragma unroll
            for (int ks = 0; ks < 2; ++ks)
#pragma unroll
                for (int j = 0; j < 4; ++j)
                    b1[ks][j] = *(const bf16x8*)(pk + (size_t)(j * 16) * K + ks * 32);
        }
        {
            const u16* lA = ldsA[0];
#pragma unroll
            for (int ks = 0; ks < 2; ++ks) {
                const int p = (ks * 4 + quad) ^ swz;
                bf16x8 af[4];
#pragma unroll
                for (int i = 0; i < 4; ++i)
                    af[i] = *(const bf16x8*)(lA + (wm + i * 16 + lhalf) * 64 + p * 8);
#pragma unroll
                for (int i = 0; i < 4; ++i)
#pragma unroll
                    for (int j = 0; j < 4; ++j)
                        acc[i][j] = __builtin_amdgcn_mfma_f32_16x16x32_bf16(
                            af[i], b0[ks][j], acc[i][j], 0, 0, 0);
            }
        }

        // ---- half 1: compute [k0+64, k0+128) from buf1/b1; stage k0+128 ----
        __syncthreads();
        if (k0 + 128 < K) {
#pragma unroll
            for (int j = 0; j < 4; ++j)
                g2lds16(pa + (size_t)(j * 8) * K, &ldsA[0][lofs + j * 512]);
            pa += 64;
            const u16* pk = pbq + (k0 + 128);
#pragma unroll
            for (int ks = 0; ks < 2; ++ks)
#pragma unroll
                for (int j = 0; j < 4; ++j)
                    b0[ks][j] = *(const bf16x8*)(pk + (size_t)(j * 16) * K + ks * 32);
        }
        {
            const u16* lA = ldsA[1];
#pragma unroll
            for (int ks = 0; ks < 2; ++ks) {
                const int p = (ks * 4 + quad) ^ swz;
                bf16x8 af[4];
#pragma unroll
                for (int i = 0; i < 4; ++i)
                    af[i] = *(const bf16x8*)(lA + (wm + i * 16 + lhalf) * 64 + p * 8);
#pragma unroll
                for (int i = 0; i < 4; ++i)
#pragma unroll
                    for (int j = 0; j < 4; ++j)
                        acc[i][j] = __builtin_amdgcn_mfma_f32_16x16x32_bf16(
                            af[i], b1[ks][j], acc[i][j], 0, 0, 0);
            }
        }
    }

    // epilogue: C/D layout col=lane&15 (n), row=quad*4+reg (m)
#pragma unroll
    for (int i = 0; i < 4; ++i) {
        const int mb = m0 + wm + i * 16 + quad * 4;
        if (MODE == 3) {   // fused QKV (branch uniform per n-tile)
#pragma unroll
            for (int j = 0; j < 4; ++j) {
                const int n = n0 + wn + j * 16 + lhalf;
                if (n < 1024) {
                    const float bb = bias[n];
#pragma unroll
                    for (int r = 0; r < 4; ++r)
                        ((u16*)Out)[(size_t)(mb + r) * 1024 + n] =
                            f2bf(acc[i][j][r] + bb);
                } else if (n < 2048) {
                    const float bb = bias2[n - 1024];
#pragma unroll
                    for (int r = 0; r < 4; ++r)
                        ((u16*)Out2)[(size_t)(mb + r) * 1024 + (n - 1024)] =
                            f2bf(acc[i][j][r] + bb);
                } else {
                    const int d = n - 2048;
                    const float bb = bias3[d];
                    const int b = mb >> 11;     // 4 consecutive m same batch
                    const int s0 = mb & 2047;
                    ushort4 w;
                    w.x = f2bf(acc[i][j][0] + bb);
                    w.y = f2bf(acc[i][j][1] + bb);
                    w.z = f2bf(acc[i][j][2] + bb);
                    w.w = f2bf(acc[i][j][3] + bb);
                    *(ushort4*)((u16*)Out3 + (size_t)b * 2097152 +
                                (size_t)d * 2048 + s0) = w;
                }
            }
        } else if (MODE == 4) {  // scores: exp + rowsum atomics
#pragma unroll
            for (int r = 0; r < 4; ++r) {
                const int m = mb + r;
                float rs = 0.f;
#pragma unroll
                for (int j = 0; j < 4; ++j) {
                    const int n = n0 + wn + j * 16 + lhalf;
                    const float e = __expf(acc[i][j][r] * scale);
                    ((u16*)Out)[bz * (size_t)sOz + (size_t)m * N + n] = f2bf(e);
                    rs += e;
                }
                rs += __shfl_xor(rs, 1, 64);
                rs += __shfl_xor(rs, 2, 64);
                rs += __shfl_xor(rs, 4, 64);
                rs += __shfl_xor(rs, 8, 64);
                if (lhalf == 0)
                    atomicAdd(&rowsum[bz * 2048 + m], rs);
            }
        } else {  // MODE 5: PV with row normalization
            float4 rs4 = *(const float4*)&rowsum[bz * 2048 + mb];
            float rinv[4];
            rinv[0] = __builtin_amdgcn_rcpf(rs4.x);
            rinv[1] = __builtin_amdgcn_rcpf(rs4.y);
            rinv[2] = __builtin_amdgcn_rcpf(rs4.z);
            rinv[3] = __builtin_amdgcn_rcpf(rs4.w);
#pragma unroll
            for (int j = 0; j < 4; ++j) {
                const int n = n0 + wn + j * 16 + lhalf;
#pragma unroll
                for (int r = 0; r < 4; ++r)
                    ((float*)Out)[bz * (size_t)sOz + (size_t)(mb + r) * N + n] =
                        acc[i][j][r] * rinv[r];
            }
        }
    }
}

extern "C" void kernel_launch(void* const* d_in, const int* in_sizes, int n_in,
                              void* d_out, int out_size, void* d_ws, size_t ws_size,
                              hipStream_t stream)
{
    const float* x  = (const float*)d_in[0];
    const float* Wq = (const float*)d_in[1];
    const float* bq = (const float*)d_in[2];
    const float* Wk = (const float*)d_in[3];
    const float* bk = (const float*)d_in[4];
    const float* Wv = (const float*)d_in[5];
    const float* bv = (const float*)d_in[6];
    float* out = (float*)d_out;

    const int B = 4, S = 2048, D = 1024;
    const long long SD = (long long)S * D;       // 2097152
    const long long SS = (long long)S * S;       // 4194304
    const long long BSD = (long long)B * SD;     // 8388608
    const long long DD = (long long)D * D;       // 1048576

    // workspace layout (bf16 = u16), total ~107 MB
    u16* xb   = (u16*)d_ws;
    u16* wall = xb   + BSD;      // [Wq;Wk;Wv] 3072 x 1024
    u16* Qb   = wall + 3 * DD;
    u16* Kb   = Qb   + BSD;
    u16* Vt   = Kb   + BSD;      // per-batch transposed: Vt[b][d][s]
    u16* Sc   = Vt   + BSD;      // exp(logits) bf16: [b][q][k]
    float* rowsum = (float*)(Sc + B * SS);   // 8192 floats

    // K0: fused casts (x + 3 weights) + rowsum zero-init
    cvt_all<<<dim3(11272), 256, 0, stream>>>(x, Wq, Wk, Wv, xb, wall, rowsum);

    // K1: fused QKV projection: A=xb (8192x1024), B=wall (3072x1024)
    gemm_bt<3><<<dim3(3 * D / 128, (B * S) / 128, 1), 256, 0, stream>>>(
        xb, wall, Qb, bq, 1.f, B * S, 3 * D, D, 0, 0, 0,
        Kb, Vt, bk, bv, nullptr);

    // K2: ScE = exp(Q K^T / sqrt(S)), rowsum += partials
    const float sc = 0.022097086912079608f;  // 1/sqrt(2048)
    gemm_bt<4><<<dim3(S / 128, S / 128, B), 256, 0, stream>>>(
        Qb, Kb, Sc, nullptr, sc, S, S, D, SD, SD, SS,
        nullptr, nullptr, nullptr, nullptr, rowsum);

    // K3: out = (ScE @ V) / rowsum   (A = ScE, B = Vt, K = S)
    gemm_bt<5><<<dim3(D / 128, S / 128, B), 256, 0, stream>>>(
        Sc, Vt, out, nullptr, 1.f, S, D, S, SS, SD, SD,
        nullptr, nullptr, nullptr, nullptr, rowsum);
}